// Round 11
// baseline (1351.969 us; speedup 1.0000x reference)
//
#include <hip/hip_runtime.h>
#include <hip/hip_bf16.h>

#define NUM_USER 300000
#define NUM_ITEM 200000
#define NTOT (NUM_USER + NUM_ITEM)
#define D 64
#define RPB 128                         // rows per bucket
#define NB ((NTOT + RPB - 1) / RPB)     // 3907 buckets
#define NBLK 256                        // fallback edge-chunk blocks
#define NBLK2 1024                      // primary edge-chunk blocks (4/CU)
#define ASTR 65                         // padded LDS acc row stride (fallback)
#define AW 8                            // waves per accum block (fallback)

// ---------- phase 1a: per-block bucket histogram (LDS atomics only) ----------

__global__ __launch_bounds__(256) void hist_bucket(
    const int* __restrict__ rows, int* __restrict__ blockhist, int nnz, int nblk)
{
    __shared__ int h[NB];   // 15.6 KB
    for (int i = threadIdx.x; i < NB; i += 256) h[i] = 0;
    __syncthreads();
    int chunk = (nnz + nblk - 1) / nblk;
    int lo = blockIdx.x * chunk;
    int hi = min(lo + chunk, nnz);
    for (int e = lo + threadIdx.x; e < hi; e += 256)
        atomicAdd(&h[__builtin_nontemporal_load(&rows[e]) >> 7], 1);
    __syncthreads();
    for (int i = threadIdx.x; i < NB; i += 256)
        blockhist[(size_t)blockIdx.x * NB + i] = h[i];
}

// ---------- phase 1b: per-bucket exclusive scan across blocks ----------

__global__ __launch_bounds__(256) void colscan(
    int* __restrict__ blockhist, int* __restrict__ coltotal, int nblk)
{
    int kb = blockIdx.x * 256 + threadIdx.x;
    if (kb >= NB) return;
    int sum = 0;
    for (int b = 0; b < nblk; b++) {
        int v = blockhist[(size_t)b * NB + kb];   // coalesced across lanes
        blockhist[(size_t)b * NB + kb] = sum;
        sum += v;
    }
    coltotal[kb] = sum;
}

// ---------- phase 1c: exclusive scan of bucket totals (single block) ----------

__global__ __launch_bounds__(256) void bucketscan(
    const int* __restrict__ coltotal, int* __restrict__ bucketbase, int nnz)
{
    __shared__ int s[256];
    int t = threadIdx.x;
    int local[16];
    int sum = 0;
    #pragma unroll
    for (int i = 0; i < 16; i++) {
        int idx = t * 16 + i;
        int c = (idx < NB) ? coltotal[idx] : 0;
        local[i] = sum;       // exclusive within thread
        sum += c;
    }
    s[t] = sum;
    __syncthreads();
    int v = sum;
    for (int off = 1; off < 256; off <<= 1) {
        int add = (t >= off) ? s[t - off] : 0;
        __syncthreads();
        s[t] += add;
        __syncthreads();
    }
    int base = s[t] - v;      // exclusive across block
    #pragma unroll
    for (int i = 0; i < 16; i++) {
        int idx = t * 16 + i;
        if (idx < NB) bucketbase[idx] = base + local[i];
    }
    if (t == 255) bucketbase[NB] = base + sum;   // == nnz
}

// ---------- phase 1d: deterministic scatter into bucket segments ----------
// FAST: rec2[pos] = {(lrow<<19)|col, val}  (8B self-contained record)
// SLOW: order[pos] = (lrow<<24)|edge_id    (fallback if workspace small)

template<bool FAST>
__global__ __launch_bounds__(256) void scatter_bucket(
    const int* __restrict__ rows, const int* __restrict__ cols,
    const float* __restrict__ vals,
    const int* __restrict__ blockhist, const int* __restrict__ bucketbase,
    int* __restrict__ order, int2* __restrict__ rec2, int nnz, int nblk)
{
    __shared__ int cur[NB];   // 15.6 KB
    for (int i = threadIdx.x; i < NB; i += 256)
        cur[i] = blockhist[(size_t)blockIdx.x * NB + i] + bucketbase[i];
    __syncthreads();
    int chunk = (nnz + nblk - 1) / nblk;
    int lo = blockIdx.x * chunk;
    int hi = min(lo + chunk, nnz);
    for (int e = lo + threadIdx.x; e < hi; e += 256) {
        int r = __builtin_nontemporal_load(&rows[e]);
        int pos = atomicAdd(&cur[r >> 7], 1);     // LDS atomic, fast
        if (FAST) {
            int   c = __builtin_nontemporal_load(&cols[e]);
            float v = __builtin_nontemporal_load(&vals[e]);
            rec2[pos] = make_int2(((r & (RPB - 1)) << 19) | c,
                                  __float_as_int(v));
        } else {
            order[pos] = ((r & (RPB - 1)) << 24) | e;
        }
    }
}

// ---------- phase 1e (fused): per-bucket count+scan -> rowptr, row-sort -----

__global__ __launch_bounds__(256) void rescatter2(
    const long long* __restrict__ rec2, const int* __restrict__ bucketbase,
    int* __restrict__ rowptr, long long* __restrict__ rec3)
{
    __shared__ int cnt[RPB];
    __shared__ int cur[RPB];
    __shared__ int s[256];
    int t = threadIdx.x;
    int kb = blockIdx.x;
    int row0 = kb * RPB;
    int start = bucketbase[kb], end = bucketbase[kb + 1];

    if (t < RPB) cnt[t] = 0;
    __syncthreads();
    // pass 1: count per-row
    for (int i = start + t; i < end; i += 256) {
        int key = (int)(rec2[i] & 0xffffffffLL);
        atomicAdd(&cnt[(key >> 19) & (RPB - 1)], 1);
    }
    __syncthreads();
    // 128-wide exclusive scan
    int v = (t < RPB) ? cnt[t] : 0;
    s[t] = v;
    __syncthreads();
    for (int off = 1; off < 256; off <<= 1) {
        int add = (t >= off) ? s[t - off] : 0;
        __syncthreads();
        s[t] += add;
        __syncthreads();
    }
    if (t < RPB) {
        int excl = s[t] - v;
        int p = start + excl;
        cur[t] = p;
        if (row0 + t <= NTOT) rowptr[row0 + t] = p;  // incl. rowptr[NTOT]=nnz
    }
    __syncthreads();
    // pass 2: scatter row-sorted self-contained records {val, col}
    for (int i = start + t; i < end; i += 256) {
        long long rc = rec2[i];
        int key = (int)(rc & 0xffffffffLL);
        int lr  = (key >> 19) & (RPB - 1);
        int pos = atomicAdd(&cur[lr], 1);        // LDS atomic
        long long outrec = (rc & 0xffffffff00000000LL)
                         | (unsigned int)(key & 0x7FFFF);
        rec3[pos] = outrec;                       // in-bucket window, L2-local
    }
}

// ---------- phase 2a: gather, one wave per row, quarter-wave float4 ---------
// ILP-4: 16 records/iter, FOUR independent accumulators -> >=4 gather
// loads in flight per wave. Clamped tail lanes all read rec3[k1-1] ->
// same embedding line -> L2 hit, negligible waste.

__global__ __launch_bounds__(256) void gather_rows(
    const float* __restrict__ users_emb, const float* __restrict__ items_emb,
    const long long* __restrict__ rec3, const int* __restrict__ rowptr,
    float* __restrict__ out, int n)
{
    int r = blockIdx.x * 4 + (threadIdx.x >> 6);
    if (r >= n) return;
    int lane = threadIdx.x & 63;
    int sub  = lane >> 4;      // which record of each group this lane serves
    int qi   = lane & 15;      // 16B chunk of the 256B embedding row
    int k0 = rowptr[r];
    int k1 = rowptr[r + 1];
    float4 a0 = make_float4(0.f, 0.f, 0.f, 0.f);
    float4 a1 = make_float4(0.f, 0.f, 0.f, 0.f);
    float4 a2 = make_float4(0.f, 0.f, 0.f, 0.f);
    float4 a3 = make_float4(0.f, 0.f, 0.f, 0.f);
    for (int g = k0; g < k1; g += 16) {
        int ka = g + sub, kb = g + 4 + sub, kc = g + 8 + sub, kd = g + 12 + sub;
        long long rca = __builtin_nontemporal_load(&rec3[ka < k1 ? ka : k1 - 1]);
        long long rcb = __builtin_nontemporal_load(&rec3[kb < k1 ? kb : k1 - 1]);
        long long rcc = __builtin_nontemporal_load(&rec3[kc < k1 ? kc : k1 - 1]);
        long long rcd = __builtin_nontemporal_load(&rec3[kd < k1 ? kd : k1 - 1]);
        int ca = (int)(rca & 0x7FFFFLL), cb = (int)(rcb & 0x7FFFFLL);
        int cc = (int)(rcc & 0x7FFFFLL), cd = (int)(rcd & 0x7FFFFLL);
        float va = (ka < k1) ? __int_as_float((int)(rca >> 32)) : 0.f;
        float vb = (kb < k1) ? __int_as_float((int)(rcb >> 32)) : 0.f;
        float vc = (kc < k1) ? __int_as_float((int)(rcc >> 32)) : 0.f;
        float vd = (kd < k1) ? __int_as_float((int)(rcd >> 32)) : 0.f;
        const float* sa = (ca < NUM_USER) ? users_emb + (size_t)ca * D
                                          : items_emb + (size_t)(ca - NUM_USER) * D;
        const float* sb = (cb < NUM_USER) ? users_emb + (size_t)cb * D
                                          : items_emb + (size_t)(cb - NUM_USER) * D;
        const float* sc = (cc < NUM_USER) ? users_emb + (size_t)cc * D
                                          : items_emb + (size_t)(cc - NUM_USER) * D;
        const float* sd = (cd < NUM_USER) ? users_emb + (size_t)cd * D
                                          : items_emb + (size_t)(cd - NUM_USER) * D;
        float4 ea = *(const float4*)(sa + (qi << 2));
        float4 eb = *(const float4*)(sb + (qi << 2));
        float4 ec = *(const float4*)(sc + (qi << 2));
        float4 ed = *(const float4*)(sd + (qi << 2));
        a0.x = fmaf(va, ea.x, a0.x); a0.y = fmaf(va, ea.y, a0.y);
        a0.z = fmaf(va, ea.z, a0.z); a0.w = fmaf(va, ea.w, a0.w);
        a1.x = fmaf(vb, eb.x, a1.x); a1.y = fmaf(vb, eb.y, a1.y);
        a1.z = fmaf(vb, eb.z, a1.z); a1.w = fmaf(vb, eb.w, a1.w);
        a2.x = fmaf(vc, ec.x, a2.x); a2.y = fmaf(vc, ec.y, a2.y);
        a2.z = fmaf(vc, ec.z, a2.z); a2.w = fmaf(vc, ec.w, a2.w);
        a3.x = fmaf(vd, ed.x, a3.x); a3.y = fmaf(vd, ed.y, a3.y);
        a3.z = fmaf(vd, ed.z, a3.z); a3.w = fmaf(vd, ed.w, a3.w);
    }
    float4 a;
    a.x = (a0.x + a1.x) + (a2.x + a3.x);
    a.y = (a0.y + a1.y) + (a2.y + a3.y);
    a.z = (a0.z + a1.z) + (a2.z + a3.z);
    a.w = (a0.w + a1.w) + (a2.w + a3.w);
    // reduce across the 4 sub-groups (lanes xor 16, then xor 32)
    a.x += __shfl_xor(a.x, 16); a.y += __shfl_xor(a.y, 16);
    a.z += __shfl_xor(a.z, 16); a.w += __shfl_xor(a.w, 16);
    a.x += __shfl_xor(a.x, 32); a.y += __shfl_xor(a.y, 32);
    a.z += __shfl_xor(a.z, 32); a.w += __shfl_xor(a.w, 32);
    if (sub == 0)
        *(float4*)(out + (size_t)r * D + (qi << 2)) = a;   // 256B per row
}

// ---------- fallback phase 2a (ws too small): bucket accum via LDS ----------

template<bool FAST>
__global__ __launch_bounds__(512) void accum_kernel(
    const float* __restrict__ users_emb, const float* __restrict__ items_emb,
    const float* __restrict__ vals, const int* __restrict__ cols,
    const long long* __restrict__ rec2, const int* __restrict__ order,
    const int* __restrict__ bucketbase, float* __restrict__ out)
{
    __shared__ float acc[RPB * ASTR];   // 33.3 KB
    int tid = threadIdx.x;
    for (int i = tid; i < RPB * ASTR; i += 512) acc[i] = 0.f;
    __syncthreads();

    int kb = blockIdx.x;
    int start = bucketbase[kb];
    int end   = bucketbase[kb + 1];
    int lane = tid & 63;
    int wid  = tid >> 6;
    int sub  = lane >> 4;
    int qi   = lane & 15;

    int span = end - start;
    int T = (span + (AW * 4 - 1)) / (AW * 4);
    int e0 = start + wid * 4 + sub;

    for (int it = 0; it < T; it++) {
        int e  = e0 + it * (AW * 4);
        int ec = max(start, min(e, end - 1));
        int ck; float v;
        if (FAST) {
            long long rc = __builtin_nontemporal_load(&rec2[ec]);
            ck = (int)(rc & 0xffffffffLL);
            v  = (e < end) ? __int_as_float((int)(rc >> 32)) : 0.f;
        } else {
            int rec  = __builtin_nontemporal_load(&order[ec]);
            int eid  = rec & 0xFFFFFF;
            int lrow = rec >> 24;
            ck = __builtin_nontemporal_load(&cols[eid]) | (lrow << 19);
            v  = (e < end) ? __builtin_nontemporal_load(&vals[eid]) : 0.f;
        }
        int cj = ck & 0x7FFFF;
        int lr = (ck >> 19) & (RPB - 1);
        const float* src = (cj < NUM_USER)
            ? users_emb + (size_t)cj * D
            : items_emb + (size_t)(cj - NUM_USER) * D;
        float4 e4 = *(const float4*)(src + (qi << 2));
        int ab = lr * ASTR + (qi << 2);
        atomicAdd(&acc[ab + 0], v * e4.x);
        atomicAdd(&acc[ab + 1], v * e4.y);
        atomicAdd(&acc[ab + 2], v * e4.z);
        atomicAdd(&acc[ab + 3], v * e4.w);
    }
    __syncthreads();

    size_t row0 = (size_t)kb * RPB;
    float4* o4 = (float4*)(out + row0 * D);
    for (int i = tid; i < RPB * (D / 4); i += 512) {
        int row = i >> 4, c4 = (i & 15) << 2;
        size_t grow = row0 + row;
        if (grow < NTOT) {
            float4 o;
            o.x = acc[row * ASTR + c4 + 0];
            o.y = acc[row * ASTR + c4 + 1];
            o.z = acc[row * ASTR + c4 + 2];
            o.w = acc[row * ASTR + c4 + 3];
            o4[i] = o;
        }
    }
}

// ---------- phase 2b: in-place out_row = leaky_relu(agg_row @ w) ----------

__global__ __launch_bounds__(256) void rowgemm_kernel(
    float* __restrict__ out, const float* __restrict__ w, int n)
{
    __shared__ float ws[D * D];   // 16 KB
    __shared__ float as[16 * D];  // 4 KB
    int tid = threadIdx.x;

    const float4* w4 = (const float4*)w;
    float4* ws4 = (float4*)ws;
    #pragma unroll
    for (int i = 0; i < 4; i++) ws4[tid + i * 256] = w4[tid + i * 256];

    size_t row0 = (size_t)blockIdx.x * 16;
    ((float4*)as)[tid] = ((const float4*)(out + row0 * D))[tid];
    __syncthreads();

    int col  = tid & 63;
    int rsub = tid >> 6;
    float res[4];
    #pragma unroll
    for (int rr = 0; rr < 4; rr++) {
        int row = rr * 4 + rsub;
        float acc = 0.f;
        #pragma unroll
        for (int k = 0; k < D; k++) {
            acc = fmaf(as[row * D + k], ws[k * D + col], acc);
        }
        res[rr] = acc > 0.f ? acc : 0.2f * acc;
    }
    #pragma unroll
    for (int rr = 0; rr < 4; rr++) {
        int row = rr * 4 + rsub;
        out[(row0 + row) * D + col] = res[rr];
    }
}

extern "C" void kernel_launch(void* const* d_in, const int* in_sizes, int n_in,
                              void* d_out, int out_size, void* d_ws, size_t ws_size,
                              hipStream_t stream) {
    const float* users_emb = (const float*)d_in[0];
    const float* items_emb = (const float*)d_in[1];
    const float* vals      = (const float*)d_in[2];
    const float* w         = (const float*)d_in[3];
    const int*   rows      = (const int*)d_in[4];
    const int*   cols      = (const int*)d_in[5];
    float* out = (float*)d_out;

    int nnz = in_sizes[2];
    int n   = NTOT;
    char* ws = (char*)d_ws;

    // ---- primary layout (NBLK2=1024 blocks; rec3 ALIASES blockhist) ----
    //   blockhist @ 0            : NBLK2*NB ints (16.0 MB)  [dead after scatter]
    //   rec3      @ 0            : nnz*8 B (80 MB)          [written in rescatter2]
    //   rec2      @ offRec2      : nnz*8 B (80 MB)
    //   coltotal  @ offMeta      : NB ints
    //   bucketbase@ offMeta+64K  : NB+1 ints
    //   rowptr    @ offMeta+128K : NTOT+1 ints (1.91 MB)
    size_t rec3Bytes = (size_t)nnz * 8ull;
    size_t bhBytes   = (size_t)NBLK2 * NB * 4ull;
    size_t offRec2   = rec3Bytes > bhBytes ? rec3Bytes : bhBytes;
    size_t offMeta   = offRec2 + (size_t)nnz * 8ull;
    size_t needP     = offMeta + (128ull << 10) + ((size_t)NTOT + 1) * 4ull;

    if (ws_size >= needP) {
        int* blockhist  = (int*)(ws);
        long long* rec3 = (long long*)(ws);
        int2* rec2      = (int2*)(ws + offRec2);
        int* coltotal   = (int*)(ws + offMeta);
        int* bucketbase = (int*)(ws + offMeta + (64ull << 10));
        int* rowptr     = (int*)(ws + offMeta + (128ull << 10));

        hist_bucket<<<NBLK2, 256, 0, stream>>>(rows, blockhist, nnz, NBLK2);
        colscan<<<(NB + 255) / 256, 256, 0, stream>>>(blockhist, coltotal, NBLK2);
        bucketscan<<<1, 256, 0, stream>>>(coltotal, bucketbase, nnz);
        scatter_bucket<true><<<NBLK2, 256, 0, stream>>>(
            rows, cols, vals, blockhist, bucketbase,
            nullptr, rec2, nnz, NBLK2);
        // blockhist dead from here; rescatter2 overwrites it with rec3
        rescatter2<<<NB, 256, 0, stream>>>(
            (const long long*)rec2, bucketbase, rowptr, rec3);
        gather_rows<<<(n + 3) / 4, 256, 0, stream>>>(
            users_emb, items_emb, (const long long*)rec3, rowptr, out, n);
        rowgemm_kernel<<<n / 16, 256, 0, stream>>>(out, w, n);
        return;
    }

    // ---- fallback layouts (proven R6/R10 compact maps, NBLK=256) ----
    int* blockhist  = (int*)(ws);
    int* coltotal   = (int*)(ws + (4ull << 20));
    int* bucketbase = (int*)(ws + (4ull << 20) + (64ull << 10));
    int* rowptr     = (int*)(ws + (6ull << 20));
    void* recbuf    = (void*)(ws + (8ull << 20));
    void* rec3buf   = (void*)(ws + (88ull << 20));

    bool fast  = ws_size >= (8ull << 20) + (size_t)nnz * 8ull;
    bool fast3 = ws_size >= (88ull << 20) + (size_t)nnz * 8ull;

    hist_bucket<<<NBLK, 256, 0, stream>>>(rows, blockhist, nnz, NBLK);
    colscan<<<(NB + 255) / 256, 256, 0, stream>>>(blockhist, coltotal, NBLK);
    bucketscan<<<1, 256, 0, stream>>>(coltotal, bucketbase, nnz);

    if (fast3) {
        scatter_bucket<true><<<NBLK, 256, 0, stream>>>(
            rows, cols, vals, blockhist, bucketbase,
            nullptr, (int2*)recbuf, nnz, NBLK);
        rescatter2<<<NB, 256, 0, stream>>>(
            (const long long*)recbuf, bucketbase, rowptr, (long long*)rec3buf);
        gather_rows<<<(n + 3) / 4, 256, 0, stream>>>(
            users_emb, items_emb, (const long long*)rec3buf, rowptr, out, n);
    } else if (fast) {
        scatter_bucket<true><<<NBLK, 256, 0, stream>>>(
            rows, cols, vals, blockhist, bucketbase,
            nullptr, (int2*)recbuf, nnz, NBLK);
        accum_kernel<true><<<NB, 512, 0, stream>>>(
            users_emb, items_emb, vals, cols,
            (const long long*)recbuf, nullptr, bucketbase, out);
    } else {
        scatter_bucket<false><<<NBLK, 256, 0, stream>>>(
            rows, cols, vals, blockhist, bucketbase,
            (int*)recbuf, nullptr, nnz, NBLK);
        accum_kernel<false><<<NB, 512, 0, stream>>>(
            users_emb, items_emb, vals, cols,
            nullptr, (const int*)recbuf, bucketbase, out);
    }

    rowgemm_kernel<<<n / 16, 256, 0, stream>>>(out, w, n);
}